// Round 9
// baseline (171.683 us; speedup 1.0000x reference)
//
#include <hip/hip_runtime.h>

#define N     4096
#define FIN   256
#define CC    256   // HEADS * F_OUT
#define HEADS 4
#define FOUT  64
#define XPITCH 266  // FIN+10 shorts = 133 dwords (odd) -> conflict-free
#define HPITCH 74   // 37 dwords (odd)
#define LOG2E 1.4426950408889634f

typedef __attribute__((ext_vector_type(8))) short bf16x8;
typedef __attribute__((ext_vector_type(4))) float f32x4;
typedef __attribute__((ext_vector_type(4))) unsigned u32x4;

// float -> bf16 (round-nearest-even) — used in GEMM kernel only
__device__ inline short f2bf(float f) {
    unsigned u = __builtin_bit_cast(unsigned, f);
    unsigned r = u + 0x7fffu + ((u >> 16) & 1u);
    return (short)(r >> 16);
}
// two floats -> packed bf16 pair by truncation (1 v_perm); softmax ratio
// cancels the systematic bias.
__device__ inline unsigned pack_trunc(float lo, float hi) {
    return __builtin_amdgcn_perm(__builtin_bit_cast(unsigned, hi),
                                 __builtin_bit_cast(unsigned, lo), 0x07060302);
}
// raw v_exp_f32 (2^x). OCML exp2f wraps this in range-fixup VALU; our args
// are |x| < 64 so the raw op is exact enough. s_nop covers the VALU-trans
// consumer hazard the compiler would otherwise insert.
__device__ inline float fast_exp2(float x) {
    float r;
    asm("v_exp_f32 %0, %1\n\ts_nop 1" : "=v"(r) : "v"(x));
    return r;
}
// one attention weight: e1/e2 pre-scaled by log2e
__device__ inline float wcalc(float e1l, float evl, unsigned bits, int jj) {
    const float el = e1l + evl;
    const float tt = fmaxf(el, 0.2f * el);    // leaky relu (scale-invariant)
    const float x  = fast_exp2(tt);
    return ((bits >> jj) & 1u) ? x : 0.f;
}

// Kernel P: adj -> bitmask (shfl-free lane-local pack), LDS-free so it runs
// at full occupancy, HBM-bound. Also zeroes d_out.
__global__ __launch_bounds__(256) void gat_pack(const int* __restrict__ adj,
                                                unsigned* __restrict__ adjb,
                                                float* __restrict__ out) {
    const int t    = threadIdx.x;
    const int bid  = blockIdx.x;
    const int lane = t & 63;
    const int w    = t >> 6;
    if (bid < 256) ((float4*)out)[bid * 256 + t] = make_float4(0.f, 0.f, 0.f, 0.f);
    const int row = bid * 4 + w;
    const int4* base = (const int4*)(adj + (size_t)row * N) + lane * 16;
    unsigned dv[2];
    #pragma unroll
    for (int p = 0; p < 2; ++p) {
        int4 c[8];
        #pragma unroll
        for (int k = 0; k < 8; ++k) c[k] = base[p * 8 + k];   // 8 in flight
        unsigned d = 0;
        #pragma unroll
        for (int k = 0; k < 8; ++k) {
            d |= (c[k].x != 0 ? 1u : 0u) << (k * 4 + 0);
            d |= (c[k].y != 0 ? 1u : 0u) << (k * 4 + 1);
            d |= (c[k].z != 0 ? 1u : 0u) << (k * 4 + 2);
            d |= (c[k].w != 0 ? 1u : 0u) << (k * 4 + 3);
        }
        dv[p] = d;
    }
    *(uint2*)(adjb + (size_t)row * 128 + lane * 2) = make_uint2(dv[0], dv[1]);
}

// Kernel G: h = x@W via MFMA (one head x 64 n-rows per block, grid 256) ->
// hF in fragment order + e1T/e2T wave-reduced.
__global__ __launch_bounds__(256) void gat_gemm(const float* __restrict__ x,
                                                const float* __restrict__ W,
                                                const float* __restrict__ a,
                                                short* __restrict__ hF,
                                                float* __restrict__ e1T,
                                                float* __restrict__ e2T) {
    __shared__ __align__(16) short xs[64][XPITCH];    // 34.0 KB
    __shared__ __align__(16) short wts[64][XPITCH];   // 34.0 KB
    __shared__ __align__(16) short hbuf[64][HPITCH];  //  9.5 KB
    const int t    = threadIdx.x;
    const int bid  = blockIdx.x;
    const int lane = t & 63;
    const int w    = t >> 6;

    const int hd = bid >> 6;
    const int n0 = (bid & 63) * 64;
    const int c0 = hd * 64;

    {   // stage x rows n0..n0+63 as bf16
        const float4* xsrc = (const float4*)(x + (size_t)n0 * FIN);
        #pragma unroll
        for (int it = 0; it < 16; ++it) {
            const int fi = it * 256 + t;
            const float4 v = xsrc[fi];
            short4 o;
            o.x = f2bf(v.x); o.y = f2bf(v.y); o.z = f2bf(v.z); o.w = f2bf(v.w);
            *(short4*)&xs[fi >> 6][(fi & 63) * 4] = o;
        }
    }
    {   // stage W^T column slice
        const int c  = t & 63;
        const int k4 = (t >> 6) * 4;
        #pragma unroll
        for (int it = 0; it < 16; ++it) {
            const int k = it * 16 + k4;
            short4 pk;
            pk.x = f2bf(W[(k + 0) * CC + c0 + c]);
            pk.y = f2bf(W[(k + 1) * CC + c0 + c]);
            pk.z = f2bf(W[(k + 2) * CC + c0 + c]);
            pk.w = f2bf(W[(k + 3) * CC + c0 + c]);
            *(short4*)&wts[c][k] = pk;
        }
    }
    __syncthreads();

    const int m = lane & 15;
    const int q = lane >> 4;

    f32x4 acc[4];
    #pragma unroll
    for (int ct = 0; ct < 4; ++ct) acc[ct] = (f32x4){0.f, 0.f, 0.f, 0.f};

    #pragma unroll
    for (int ks = 0; ks < 8; ++ks) {
        const bf16x8 af = *(const bf16x8*)&xs[w * 16 + m][ks * 32 + q * 8];
        #pragma unroll
        for (int ct = 0; ct < 4; ++ct) {
            const bf16x8 bf_ = *(const bf16x8*)&wts[ct * 16 + m][ks * 32 + q * 8];
            acc[ct] = __builtin_amdgcn_mfma_f32_16x16x32_bf16(af, bf_, acc[ct], 0, 0, 0);
        }
    }

    // e1/e2 from fp32 acc (C layout: row=q*4+r, col=ct*16+m)
    const float a1v[4] = {a[m], a[16 + m], a[32 + m], a[48 + m]};
    const float a2v[4] = {a[64 + m], a[80 + m], a[96 + m], a[112 + m]};
    #pragma unroll
    for (int r = 0; r < 4; ++r) {
        float s1 = 0.f, s2 = 0.f;
        #pragma unroll
        for (int ct = 0; ct < 4; ++ct) {
            s1 = fmaf(acc[ct][r], a1v[ct], s1);
            s2 = fmaf(acc[ct][r], a2v[ct], s2);
        }
        #pragma unroll
        for (int sh = 1; sh < 16; sh <<= 1) {
            s1 += __shfl_xor(s1, sh, 64);
            s2 += __shfl_xor(s2, sh, 64);
        }
        if (m == 0) {
            const int n = n0 + w * 16 + q * 4 + r;
            e1T[hd * N + n] = s1;
            e2T[hd * N + n] = s2;
        }
    }

    // transpose h tile to hbuf[c][n-local]
    #pragma unroll
    for (int ct = 0; ct < 4; ++ct)
        #pragma unroll
        for (int r = 0; r < 4; ++r)
            hbuf[ct * 16 + m][w * 16 + q * 4 + r] = f2bf(acc[ct][r]);
    __syncthreads();

    // write hF in fragment order: frag(jc, ft) lane lp holds
    // h[f=ft*16+(lp&15)][j = jc*32 + (lp>>4)*8 + 0..7]
    {
        const int lp = t & 63;
        const int ft = t >> 6;
        const int mm = lp & 15;
        const int qq = lp >> 4;
        #pragma unroll
        for (int c2 = 0; c2 < 2; ++c2) {
            const bf16x8 hv = *(const bf16x8*)&hbuf[ft * 16 + mm][c2 * 32 + qq * 8];
            const size_t jc = (size_t)(n0 >> 5) + c2;
            *(bf16x8*)(hF + ((((size_t)hd * 128 + jc) * 4 + ft) * 64 + lp) * 8) = hv;
        }
    }
}

// Kernel 2: masked-softmax aggregation via MFMA. 16 i-rows x one head x
// full j per block; 8 waves = 8 j-stripes x 16 steps. Grid 1024, XCD-affine
// i-tiles. __launch_bounds__(512,6): ~85 unified regs (16 AGPR acc + ~69
// VGPR working set) — enough registers for clean weight-gen codegen while
// keeping 3 blocks/CU resident.
__global__ __launch_bounds__(512, 6) void gat_k2(const short* __restrict__ hF,
                                                 const unsigned* __restrict__ adjb,
                                                 const float* __restrict__ e1T,
                                                 const float* __restrict__ e2T,
                                                 float* __restrict__ out) {
    __shared__ float obuf[16][64];                //  4 KB
    __shared__ float zbuf[8][16];                 //  0.5 KB
    __shared__ __align__(16) float e2lds[N];      // 16 KB (log2e-scaled)
    __shared__ unsigned adjlds[16 * 129];         //  8.25 KB (odd pitch)
    const int t    = threadIdx.x;
    const int lane = t & 63;
    const int g    = t >> 6;                      // j-stripe 0..7
    const int bid  = blockIdx.x;
    const int hd   = (bid >> 3) & 3;
    const int it   = (bid & 7) | ((bid >> 5) << 3);   // XCD-affine i-tile
    const int i0   = it * 16;
    const int m    = lane & 15;
    const int q    = lane >> 4;

    {   float* ob = &obuf[0][0]; ob[t] = 0.f; ob[t + 512] = 0.f; }
    {   // stage e2 (this head, all j), pre-scaled by log2e
        const float4* src = (const float4*)(e2T + (size_t)hd * N);
        float4* dst = (float4*)e2lds;
        float4 v0 = src[t], v1 = src[t + 512];
        v0.x *= LOG2E; v0.y *= LOG2E; v0.z *= LOG2E; v0.w *= LOG2E;
        v1.x *= LOG2E; v1.y *= LOG2E; v1.z *= LOG2E; v1.w *= LOG2E;
        dst[t] = v0; dst[t + 512] = v1;
    }
    {   // stage adj bits for 16 i-rows (128 dw/row, 129-dw pitch)
        const unsigned* src = adjb + (size_t)i0 * 128;
        #pragma unroll
        for (int r = 0; r < 4; ++r) {
            const int idx = t + r * 512;
            adjlds[(idx >> 7) * 129 + (idx & 127)] = src[idx];
        }
    }
    __syncthreads();

    const float e1v = e1T[hd * N + i0 + m] * LOG2E;

    f32x4 accf[4];
    #pragma unroll
    for (int ft = 0; ft < 4; ++ft) accf[ft] = (f32x4){0.f, 0.f, 0.f, 0.f};
    float zacc = 0.f;

    // chunk jc = g + step*8; layout hF[hd][jc][ft][lane][8]
    const short* hbase = hF + (((size_t)hd * 128 + g) * 256 + lane) * 8;
    const unsigned char* abyte = ((const unsigned char*)adjlds) + m * 516 + g * 4 + q;

    for (int step = 0; step < 16; ++step) {
        const short* hstep = hbase + (size_t)step * 16384;   // 8 chunks * 2048
        const bf16x8 b0 = *(const bf16x8*)(hstep);
        const bf16x8 b1 = *(const bf16x8*)(hstep + 512);
        const bf16x8 b2 = *(const bf16x8*)(hstep + 1024);
        const bf16x8 b3 = *(const bf16x8*)(hstep + 1536);

        const int jbase = g * 32 + step * 256 + q * 8;
        const float4 ce0 = *(const float4*)&e2lds[jbase];
        const float4 ce1 = *(const float4*)&e2lds[jbase + 4];
        const unsigned bits = (unsigned)abyte[step * 32];

        const float evl[8] = {ce0.x, ce0.y, ce0.z, ce0.w, ce1.x, ce1.y, ce1.z, ce1.w};
        u32x4 pk;
        #pragma unroll
        for (int p = 0; p < 4; ++p) {
            const float w0 = wcalc(e1v, evl[2 * p],     bits, 2 * p);
            const float w1 = wcalc(e1v, evl[2 * p + 1], bits, 2 * p + 1);
            zacc += w0 + w1;
            pk[p] = pack_trunc(w0, w1);
        }
        const bf16x8 afrag = __builtin_bit_cast(bf16x8, pk);

        accf[0] = __builtin_amdgcn_mfma_f32_16x16x32_bf16(afrag, b0, accf[0], 0, 0, 0);
        accf[1] = __builtin_amdgcn_mfma_f32_16x16x32_bf16(afrag, b1, accf[1], 0, 0, 0);
        accf[2] = __builtin_amdgcn_mfma_f32_16x16x32_bf16(afrag, b2, accf[2], 0, 0, 0);
        accf[3] = __builtin_amdgcn_mfma_f32_16x16x32_bf16(afrag, b3, accf[3], 0, 0, 0);
    }

    // Z stripe partial per row m
    zacc += __shfl_xor(zacc, 16, 64);
    zacc += __shfl_xor(zacc, 32, 64);
    if (lane < 16) zbuf[g][lane] = zacc;

    // numerator: C layout row=q*4+r, col=ft*16+m
    #pragma unroll
    for (int ft = 0; ft < 4; ++ft)
        #pragma unroll
        for (int r = 0; r < 4; ++r)
            atomicAdd(&obuf[q * 4 + r][ft * 16 + m], accf[ft][r]);
    __syncthreads();

    #pragma unroll
    for (int rep = 0; rep < 2; ++rep) {
        const int idx = t + rep * 512;
        const int ii  = idx >> 6;     // 0..15
        const int ff  = idx & 63;
        float Z = 0.f;
        #pragma unroll
        for (int gg = 0; gg < 8; ++gg) Z += zbuf[gg][ii];
        atomicAdd(&out[(size_t)(i0 + ii) * FOUT + ff], 0.25f * obuf[ii][ff] / Z);
    }
}

extern "C" void kernel_launch(void* const* d_in, const int* in_sizes, int n_in,
                              void* d_out, int out_size, void* d_ws, size_t ws_size,
                              hipStream_t stream) {
    const float* x   = (const float*)d_in[0];
    const int*   adj = (const int*)d_in[1];
    const float* W   = (const float*)d_in[2];
    const float* a   = (const float*)d_in[3];
    float* out = (float*)d_out;

    short*    hF   = (short*)d_ws;                           // 2 MB
    float*    e1T  = (float*)(hF + (size_t)HEADS * FOUT * N);
    float*    e2T  = e1T + (size_t)HEADS * N;
    unsigned* adjb = (unsigned*)(e2T + (size_t)HEADS * N);   // 2 MB

    gat_pack<<<1024, 256, 0, stream>>>(adj, adjb, out);
    gat_gemm<<<256, 256, 0, stream>>>(x, W, a, hF, e1T, e2T);
    gat_k2<<<1024, 512, 0, stream>>>(hF, adjb, e1T, e2T, out);
}